// Round 11
// baseline (4168.056 us; speedup 1.0000x reference)
//
#include <hip/hip_runtime.h>

// ---------------------------------------------------------------------------
// LSTM_NER_TeacherForcing: B=32, T=512, E=512, H=512, V=50000, C=32, L=2
// embed -> [mfma gemm xw -> persistent scan] x2 -> classifier
// Round 11 (scan, on R9 base):
//   - xw ONE-STEP REGISTER PREFETCH issued post-stage: removes xw's HBM
//     latency from the poll-wait path (vmcnt is FIFO: R9's pre-poll xw load
//     delayed every first packet check by the xw miss);
//   - sleep-free PREDICATED re-poll (reload only invalid packets, pure spin);
//   - grid back to 256 blocks x 256 thr (best measured, R9).
// ---------------------------------------------------------------------------

#define BB 32
#define TT 512
#define EE 512
#define HH 512
#define NG 2048   // 4*H gate rows
#define CC 32

typedef __attribute__((ext_vector_type(8))) short short8v;
typedef __attribute__((ext_vector_type(4))) float float4v;
typedef unsigned long long u64;

__device__ __forceinline__ float bf2f(unsigned short u) {
    return __uint_as_float(((unsigned)u) << 16);
}
__device__ __forceinline__ float bf_lo(unsigned u) { return __uint_as_float(u << 16); }
__device__ __forceinline__ float bf_hi(unsigned u) { return __uint_as_float(u & 0xffff0000u); }
__device__ __forceinline__ unsigned short f2bf(float f) {
    unsigned u = __float_as_uint(f);
    u += 0x7fffu + ((u >> 16) & 1u);   // RNE
    return (unsigned short)(u >> 16);
}
__device__ __forceinline__ unsigned pk2(float a, float b) {
    return (unsigned)f2bf(a) | ((unsigned)f2bf(b) << 16);
}
__device__ __forceinline__ float fast_sigmoid(float x) {
    return 1.f / (1.f + __expf(-x));
}
__device__ __forceinline__ float fast_tanh(float x) {
    x = fminf(fmaxf(x, -15.f), 15.f);
    float e = __expf(2.f * x);
    return (e - 1.f) / (e + 1.f);
}

// ---------------------------------------------------------------------------
// 1) Embedding gather: h0[b,t,e] = emb[x[b,t]][e]  (f32 -> bf16)
__global__ __launch_bounds__(256)
void embed_k(const int* __restrict__ x, const float* __restrict__ emb,
             unsigned short* __restrict__ h0) {
    int idx = blockIdx.x * 256 + threadIdx.x;    // one float4 each
    int row = idx >> 7;                          // E/4 = 128 chunks per row
    int c4  = idx & 127;
    int tok = x[row];
    float4 v = *(const float4*)(emb + ((size_t)tok << 9) + (c4 << 2));
    ushort4 o;
    o.x = f2bf(v.x); o.y = f2bf(v.y); o.z = f2bf(v.z); o.w = f2bf(v.w);
    *(ushort4*)(h0 + ((size_t)row << 9) + (c4 << 2)) = o;
}

// ---------------------------------------------------------------------------
// 2) Input GEMM via MFMA. 128x128 tile, BK=64, 512 thr (8 waves, 2x4 grid,
// each wave 64x32 = 4x2 16x16 frags). LDS rows 128B, XOR-swizzled (r&7)<<4.
// Output PERMUTED: xwp[((jb*512+t)*32+b)*64 + gate*16+jj] (normal stores).
__global__ __launch_bounds__(512)
void gemm_xw(const unsigned short* __restrict__ A, const float* __restrict__ Bw,
             const float* __restrict__ bih, const float* __restrict__ bhh,
             unsigned short* __restrict__ Cp, int M, int K) {
    __shared__ __align__(16) unsigned char As[128 * 128];  // 128 rows x 64 bf16
    __shared__ __align__(16) unsigned char Bs[128 * 128];
    const int bn = blockIdx.x & 15, bm = blockIdx.x >> 4;
    const int tid = threadIdx.x;
    const int wv = tid >> 6, lane = tid & 63;
    const int wr = wv >> 2, wc = wv & 3;          // wave tile: rows wr*64, cols wc*32
    const int srow = tid >> 2, skc = (tid & 3) * 16;   // staging: row, bf16-chunk
    const unsigned sswz = (srow & 7) << 4;
    const int fr = lane & 15, fkb = (lane >> 4) * 16;  // frag row, k-byte base

    float4v acc[4][2];
#pragma unroll
    for (int i = 0; i < 4; ++i) { acc[i][0] = (float4v)(0.f); acc[i][1] = (float4v)(0.f); }

    const unsigned short* arow_p = A + (size_t)(bm * 128 + srow) * K + skc;
    const float* brow_p = Bw + (size_t)(bn * 128 + srow) * K + skc;
    unsigned char* const as_row = As + srow * 128;
    unsigned char* const bs_row = Bs + srow * 128;
    const int sb0 = skc * 2;

    for (int k0 = 0; k0 < K; k0 += 64) {
        // stage A: 16 bf16 (2x uint4)
        uint4 a0 = *(const uint4*)(arow_p + k0);
        uint4 a1 = *(const uint4*)(arow_p + k0 + 8);
        // stage B: 16 f32 -> 16 bf16
        float4 b0 = *(const float4*)(brow_p + k0);
        float4 b1 = *(const float4*)(brow_p + k0 + 4);
        float4 b2 = *(const float4*)(brow_p + k0 + 8);
        float4 b3 = *(const float4*)(brow_p + k0 + 12);
        *(uint4*)(as_row + ((sb0     ) ^ sswz)) = a0;
        *(uint4*)(as_row + ((sb0 + 16) ^ sswz)) = a1;
        uint4 bp0 = make_uint4(pk2(b0.x, b0.y), pk2(b0.z, b0.w), pk2(b1.x, b1.y), pk2(b1.z, b1.w));
        uint4 bp1 = make_uint4(pk2(b2.x, b2.y), pk2(b2.z, b2.w), pk2(b3.x, b3.y), pk2(b3.z, b3.w));
        *(uint4*)(bs_row + ((sb0     ) ^ sswz)) = bp0;
        *(uint4*)(bs_row + ((sb0 + 16) ^ sswz)) = bp1;
        __syncthreads();

#pragma unroll
        for (int kt = 0; kt < 2; ++kt) {
            const int cb = kt * 64 + fkb;
            short8v af[4], bf[2];
#pragma unroll
            for (int mt = 0; mt < 4; ++mt) {
                const int r = wr * 64 + mt * 16 + fr;
                af[mt] = *(const short8v*)(As + r * 128 + (cb ^ ((r & 7) << 4)));
            }
#pragma unroll
            for (int nt = 0; nt < 2; ++nt) {
                const int r = wc * 32 + nt * 16 + fr;
                bf[nt] = *(const short8v*)(Bs + r * 128 + (cb ^ ((r & 7) << 4)));
            }
#pragma unroll
            for (int mt = 0; mt < 4; ++mt) {
                acc[mt][0] = __builtin_amdgcn_mfma_f32_16x16x32_bf16(af[mt], bf[0], acc[mt][0], 0, 0, 0);
                acc[mt][1] = __builtin_amdgcn_mfma_f32_16x16x32_bf16(af[mt], bf[1], acc[mt][1], 0, 0, 0);
            }
        }
        __syncthreads();
    }

    const int r4 = (lane >> 4) * 4;
#pragma unroll
    for (int nt = 0; nt < 2; ++nt) {
        const int nglob = bn * 128 + wc * 32 + nt * 16 + fr;
        const float bias = bih[nglob] + bhh[nglob];
        const int gate = nglob >> 9;
        const int jbv = (nglob & 511) >> 4;
        const int loc = gate * 16 + (nglob & 15);
#pragma unroll
        for (int mt = 0; mt < 4; ++mt) {
#pragma unroll
            for (int i = 0; i < 4; ++i) {
                const int mglob = bm * 128 + wr * 64 + mt * 16 + r4 + i;
                const int b = mglob >> 9, t = mglob & 511;
                Cp[(((size_t)jbv * 512 + t) * 32 + b) * 64 + loc] =
                    f2bf(acc[mt][nt][i] + bias);
            }
        }
    }
}

// ---------------------------------------------------------------------------
// 3) Persistent bidirectional LSTM scan. grid = 256 blocks, 256 thr (4 waves).
// grp = blk&7 (dir*4+bg), jb = blk>>3. Wave w = gate type w (Whh in VGPRs).
// h crosses blocks as 64-bit {seq|2xbf16} packets, relaxed agent atomics,
// 4-slot rotation; sleep-free predicated data-poll; xw reg-prefetched 1 step.
__global__ __launch_bounds__(256, 1)
void lstm_scan(const float* __restrict__ WhhF, const float* __restrict__ WhhB,
               const unsigned short* __restrict__ xwF, const unsigned short* __restrict__ xwB,
               unsigned short* __restrict__ outcat,   // (B,T,1024) bf16
               u64* __restrict__ h_pp) {              // [(slot*2+dir)*32+b][256] u64
    __shared__ __align__(16) unsigned char hs[16384];  // bf16 [16 rows][512 k], swizzled
    __shared__ float gsh[4][8][16];
    __shared__ unsigned xsh[2][256];

    const int blk = blockIdx.x;
    const int grp = blk & 7, jb = blk >> 3;
    const int bg = grp & 3, dir = grp >> 2;
    const int tid = threadIdx.x;
    const int wv = tid >> 6, lane = tid & 63;
    const float* Whh = dir ? WhhB : WhhF;
    const unsigned short* xw = dir ? xwB : xwF;
    const int js = jb << 4;

    // ---- preload weights into registers: wave wv = gate type wv ----
    short8v bw[16];
    {
        const float* wrow = Whh + (size_t)(wv * 512 + js + (lane & 15)) * HH
                            + (lane >> 4) * 8;
#pragma unroll
        for (int kk = 0; kk < 16; ++kk) {
            const float4 f0 = *(const float4*)(wrow + kk * 32);
            const float4 f1 = *(const float4*)(wrow + kk * 32 + 4);
            short8v b;
            b[0] = (short)f2bf(f0.x); b[1] = (short)f2bf(f0.y);
            b[2] = (short)f2bf(f0.z); b[3] = (short)f2bf(f0.w);
            b[4] = (short)f2bf(f1.x); b[5] = (short)f2bf(f1.y);
            b[6] = (short)f2bf(f1.z); b[7] = (short)f2bf(f1.w);
            bw[kk] = b;
        }
    }

    // zero hs rows 8..15 once (A-frag rows 8-15 are never re-written)
    for (int i = tid; i < 8 * 64; i += 256) {
        int r = 8 + (i >> 6), c = i & 63;
        *(uint4*)(hs + r * 1024 + ((c * 16) ^ ((r & 7) << 4))) = make_uint4(0, 0, 0, 0);
    }

    float c_st = 0.f;
    // stage coords: thread -> row tid>>5 (0..7), k-lane tid&31
    const int srow = tid >> 5, kcol = tid & 31;
    const unsigned swz_w = (srow & 7) << 4;
    // A-frag read coords
    const int arow = lane & 15, ag16 = (lane >> 4) * 16;
    const unsigned swz_r = (arow & 7) << 4;
    __syncthreads();

    // prime the xw register pipeline (normal load; caches fine)
    unsigned xv_cur = *(const unsigned*)(
        xw + (((size_t)jb * 512 + (dir ? TT - 1 : 0)) * 32 + bg * 8) * 64 + 2 * tid);
    unsigned xv_next = 0;

    for (int t = 0; t < TT; ++t) {
        const int tt = dir ? (TT - 1 - t) : t;

        // ---- stage h: sleep-free predicated poll until seq==t ----
        {
            const u64* hsrc =
                h_pp + ((size_t)((t & 3) * 2 + dir) * BB + bg * 8 + srow) * 256;
            const unsigned sq = (unsigned)t;
            u64 v0 = __hip_atomic_load(hsrc + kcol,       __ATOMIC_RELAXED, __HIP_MEMORY_SCOPE_AGENT);
            u64 v1 = __hip_atomic_load(hsrc + kcol + 32,  __ATOMIC_RELAXED, __HIP_MEMORY_SCOPE_AGENT);
            u64 v2 = __hip_atomic_load(hsrc + kcol + 64,  __ATOMIC_RELAXED, __HIP_MEMORY_SCOPE_AGENT);
            u64 v3 = __hip_atomic_load(hsrc + kcol + 96,  __ATOMIC_RELAXED, __HIP_MEMORY_SCOPE_AGENT);
            u64 v4 = __hip_atomic_load(hsrc + kcol + 128, __ATOMIC_RELAXED, __HIP_MEMORY_SCOPE_AGENT);
            u64 v5 = __hip_atomic_load(hsrc + kcol + 160, __ATOMIC_RELAXED, __HIP_MEMORY_SCOPE_AGENT);
            u64 v6 = __hip_atomic_load(hsrc + kcol + 192, __ATOMIC_RELAXED, __HIP_MEMORY_SCOPE_AGENT);
            u64 v7 = __hip_atomic_load(hsrc + kcol + 224, __ATOMIC_RELAXED, __HIP_MEMORY_SCOPE_AGENT);
            bool k0 = (unsigned)(v0 >> 32) == sq, k1 = (unsigned)(v1 >> 32) == sq;
            bool k2 = (unsigned)(v2 >> 32) == sq, k3 = (unsigned)(v3 >> 32) == sq;
            bool k4 = (unsigned)(v4 >> 32) == sq, k5 = (unsigned)(v5 >> 32) == sq;
            bool k6 = (unsigned)(v6 >> 32) == sq, k7 = (unsigned)(v7 >> 32) == sq;
            while (!(k0 && k1 && k2 && k3 && k4 && k5 && k6 && k7)) {
                if (!k0) { v0 = __hip_atomic_load(hsrc + kcol,       __ATOMIC_RELAXED, __HIP_MEMORY_SCOPE_AGENT); k0 = (unsigned)(v0 >> 32) == sq; }
                if (!k1) { v1 = __hip_atomic_load(hsrc + kcol + 32,  __ATOMIC_RELAXED, __HIP_MEMORY_SCOPE_AGENT); k1 = (unsigned)(v1 >> 32) == sq; }
                if (!k2) { v2 = __hip_atomic_load(hsrc + kcol + 64,  __ATOMIC_RELAXED, __HIP_MEMORY_SCOPE_AGENT); k2 = (unsigned)(v2 >> 32) == sq; }
                if (!k3) { v3 = __hip_atomic_load(hsrc + kcol + 96,  __ATOMIC_RELAXED, __HIP_MEMORY_SCOPE_AGENT); k3 = (unsigned)(v3 >> 32) == sq; }
                if (!k4) { v4 = __hip_atomic_load(hsrc + kcol + 128, __ATOMIC_RELAXED, __HIP_MEMORY_SCOPE_AGENT); k4 = (unsigned)(v4 >> 32) == sq; }
                if (!k5) { v5 = __hip_atomic_load(hsrc + kcol + 160, __ATOMIC_RELAXED, __HIP_MEMORY_SCOPE_AGENT); k5 = (unsigned)(v5 >> 32) == sq; }
                if (!k6) { v6 = __hip_atomic_load(hsrc + kcol + 192, __ATOMIC_RELAXED, __HIP_MEMORY_SCOPE_AGENT); k6 = (unsigned)(v6 >> 32) == sq; }
                if (!k7) { v7 = __hip_atomic_load(hsrc + kcol + 224, __ATOMIC_RELAXED, __HIP_MEMORY_SCOPE_AGENT); k7 = (unsigned)(v7 >> 32) == sq; }
            }
            xsh[t & 1][tid] = xv_cur;
            unsigned char* hrow = hs + srow * 1024;
            *(unsigned*)(hrow + ((4 * kcol +   0) ^ swz_w)) = (unsigned)v0;
            *(unsigned*)(hrow + ((4 * kcol + 128) ^ swz_w)) = (unsigned)v1;
            *(unsigned*)(hrow + ((4 * kcol + 256) ^ swz_w)) = (unsigned)v2;
            *(unsigned*)(hrow + ((4 * kcol + 384) ^ swz_w)) = (unsigned)v3;
            *(unsigned*)(hrow + ((4 * kcol + 512) ^ swz_w)) = (unsigned)v4;
            *(unsigned*)(hrow + ((4 * kcol + 640) ^ swz_w)) = (unsigned)v5;
            *(unsigned*)(hrow + ((4 * kcol + 768) ^ swz_w)) = (unsigned)v6;
            *(unsigned*)(hrow + ((4 * kcol + 896) ^ swz_w)) = (unsigned)v7;
        }
        // prefetch next step's xw into a register: its latency hides under
        // MFMA + gates + next step's poll (it is NOT in the poll-wait chain).
        if (t + 1 < TT) {
            const int ttn = dir ? (TT - 2 - t) : (t + 1);
            xv_next = *(const unsigned*)(
                xw + (((size_t)jb * 512 + ttn) * 32 + bg * 8) * 64 + 2 * tid);
        }
        __syncthreads();   // (1) h staged + xsh written

        // ---- MFMA: wave wv computes gates[wv][b 0..7][jj 0..15] over K=512 ----
        {
            float4v a0 = (float4v)(0.0f), a1 = (float4v)(0.0f);
#pragma unroll
            for (int kk = 0; kk < 16; kk += 2) {
                short8v af0 = *(const short8v*)(hs + arow * 1024 +
                                  (((kk * 64) + ag16) ^ swz_r));
                short8v af1 = *(const short8v*)(hs + arow * 1024 +
                                  ((((kk + 1) * 64) + ag16) ^ swz_r));
                a0 = __builtin_amdgcn_mfma_f32_16x16x32_bf16(af0, bw[kk], a0, 0, 0, 0);
                a1 = __builtin_amdgcn_mfma_f32_16x16x32_bf16(af1, bw[kk + 1], a1, 0, 0, 0);
            }
            if (lane < 32) {   // rows 0..7 valid: row=(lane>>4)*4+reg, col=lane&15
#pragma unroll
                for (int reg = 0; reg < 4; ++reg) {
                    gsh[wv][(lane >> 4) * 4 + reg][lane & 15] = a0[reg] + a1[reg];
                }
            }
        }
        __syncthreads();   // (2) gates in gsh

        // ---- gate nonlinearity + state update (tid<128: b=tid>>4, jj=tid&15) ----
        if (tid < 128) {
            const int bl = tid >> 4, jj = tid & 15;
            const unsigned short* xp = (const unsigned short*)xsh[t & 1];
            const int vb = bl * 64 + jj;
            float gi = gsh[0][bl][jj] + bf2f(xp[vb]);
            float gf = gsh[1][bl][jj] + bf2f(xp[vb + 16]);
            float gg = gsh[2][bl][jj] + bf2f(xp[vb + 32]);
            float go = gsh[3][bl][jj] + bf2f(xp[vb + 48]);
            float si = fast_sigmoid(gi);
            float sf = fast_sigmoid(gf);
            float so = fast_sigmoid(go);
            c_st = sf * c_st + si * fast_tanh(gg);
            float hv = so * fast_tanh(c_st);
            const unsigned short hb16 = f2bf(hv);
            const int b_glob = bg * 8 + bl;
            // pack pair (jj even|odd) + seq into one 64-bit packet
            unsigned hv32 = hb16;
            unsigned other = (unsigned)__shfl_xor((int)hv32, 1);
            if (!(tid & 1)) {
                u64 pkt = ((u64)(unsigned)(t + 1) << 32) | (u64)(hv32 | (other << 16));
                __hip_atomic_store(
                    &h_pp[((size_t)(((t + 1) & 3) * 2 + dir) * BB + b_glob) * 256
                          + jb * 8 + (jj >> 1)],
                    pkt, __ATOMIC_RELAXED, __HIP_MEMORY_SCOPE_AGENT);
            }
            outcat[((size_t)b_glob * TT + tt) * 1024 + dir * HH + js + jj] = hb16;
        }
        xv_cur = xv_next;
        // no third barrier: xsh is double-buffered; hs/gsh protected by (1),(2)
    }
}

// ---------------------------------------------------------------------------
// 4) Classifier + log_softmax, transposed write (B,C,T).
__global__ __launch_bounds__(256)
void classifier_k(const unsigned short* __restrict__ hcat, const float* __restrict__ truth,
                  const int* __restrict__ tf, const float* __restrict__ Wc,
                  const float* __restrict__ bc, float* __restrict__ out) {
    __shared__ float feat[8][1024];
    __shared__ float featp[8];
    const int tid = threadIdx.x;
    const int bt0 = blockIdx.x * 8;
    for (int i = tid; i < 8 * 128; i += 256) {   // 8 rows x 128 chunks(8 vals)
        int bl = i >> 7, ch = i & 127;
        uint4 u = *(const uint4*)(hcat + (size_t)(bt0 + bl) * 1024 + ch * 8);
        *(float4*)&feat[bl][ch * 8] = make_float4(bf_lo(u.x), bf_hi(u.x), bf_lo(u.y), bf_hi(u.y));
        *(float4*)&feat[bl][ch * 8 + 4] = make_float4(bf_lo(u.z), bf_hi(u.z), bf_lo(u.w), bf_hi(u.w));
    }
    if (tid < 8) {
        int bt = bt0 + tid;
        int t = bt & 511;
        featp[tid] = (t > 0 && tf[0] != 0) ? truth[bt - 1] : 0.f;
    }
    __syncthreads();
    const int bl = tid >> 5, c = tid & 31;
    const int bt = bt0 + bl;
    float acc = featp[bl] * Wc[c * 1025] + bc[c];
    const float* w = Wc + c * 1025 + 1;
    for (int f4 = 0; f4 < 256; ++f4) {
        const float4 fv = *(const float4*)&feat[bl][f4 * 4];
        acc = fmaf(fv.x, w[f4 * 4 + 0],
              fmaf(fv.y, w[f4 * 4 + 1],
              fmaf(fv.z, w[f4 * 4 + 2],
              fmaf(fv.w, w[f4 * 4 + 3], acc))));
    }
    float m = acc;
#pragma unroll
    for (int mk = 16; mk; mk >>= 1) m = fmaxf(m, __shfl_xor(m, mk));
    float e = expf(acc - m);
    float s = e;
#pragma unroll
    for (int mk = 16; mk; mk >>= 1) s += __shfl_xor(s, mk);
    float lse = m + logf(s);
    int b = bt >> 9, t = bt & 511;
    out[((size_t)b * CC + c) * TT + t] = acc - lse;
}

// ---------------------------------------------------------------------------
extern "C" void kernel_launch(void* const* d_in, const int* in_sizes, int n_in,
                              void* d_out, int out_size, void* d_ws, size_t ws_size,
                              hipStream_t stream) {
    const int* x = (const int*)d_in[0];
    const float* truth = (const float*)d_in[1];
    const int* tf = (const int*)d_in[2];
    const float* emb = (const float*)d_in[3];
    const float* Wih0f = (const float*)d_in[4];
    const float* Whh0f = (const float*)d_in[5];
    const float* bih0f = (const float*)d_in[6];
    const float* bhh0f = (const float*)d_in[7];
    const float* Wih0b = (const float*)d_in[8];
    const float* Whh0b = (const float*)d_in[9];
    const float* bih0b = (const float*)d_in[10];
    const float* bhh0b = (const float*)d_in[11];
    const float* Wih1f = (const float*)d_in[12];
    const float* Whh1f = (const float*)d_in[13];
    const float* bih1f = (const float*)d_in[14];
    const float* bhh1f = (const float*)d_in[15];
    const float* Wih1b = (const float*)d_in[16];
    const float* Whh1b = (const float*)d_in[17];
    const float* bih1b = (const float*)d_in[18];
    const float* bhh1b = (const float*)d_in[19];
    const float* Wc = (const float*)d_in[20];
    const float* bc = (const float*)d_in[21];
    float* out = (float*)d_out;

    // ws layout (bytes)
    const size_t off_h0  = 0;                       // (B,T,512) bf16 : 16 MB
    const size_t off_xwf = 16777216;                // perm (32,512,32,64) bf16: 64 MB
    const size_t off_xwb = off_xwf + 67108864;
    const size_t off_hc1 = off_xwb + 67108864;      // (B,T,1024) bf16: 32 MB
    const size_t off_hc2 = off_hc1 + 33554432;
    const size_t off_hpp = off_hc2 + 33554432;      // u64 packets: 4*2*32*256*8 = 512 KB
    const size_t need = off_hpp + 524288;
    if (ws_size < need) return;

    char* ws = (char*)d_ws;
    unsigned short* h0  = (unsigned short*)(ws + off_h0);
    unsigned short* xwf = (unsigned short*)(ws + off_xwf);
    unsigned short* xwb = (unsigned short*)(ws + off_xwb);
    unsigned short* hc1 = (unsigned short*)(ws + off_hc1);
    unsigned short* hc2 = (unsigned short*)(ws + off_hc2);
    u64*            hpp = (u64*)(ws + off_hpp);

    embed_k<<<8192, 256, 0, stream>>>(x, emb, h0);

    // layer 0
    gemm_xw<<<2048, 512, 0, stream>>>(h0, Wih0f, bih0f, bhh0f, xwf, BB * TT, EE);
    gemm_xw<<<2048, 512, 0, stream>>>(h0, Wih0b, bih0b, bhh0b, xwb, BB * TT, EE);
    (void)hipMemsetAsync(ws + off_hpp, 0, 524288, stream);
    lstm_scan<<<256, 256, 0, stream>>>(Whh0f, Whh0b, xwf, xwb, hc1, hpp);

    // layer 1
    gemm_xw<<<2048, 512, 0, stream>>>(hc1, Wih1f, bih1f, bhh1f, xwf, BB * TT, 1024);
    gemm_xw<<<2048, 512, 0, stream>>>(hc1, Wih1b, bih1b, bhh1b, xwb, BB * TT, 1024);
    (void)hipMemsetAsync(ws + off_hpp, 0, 524288, stream);
    lstm_scan<<<256, 256, 0, stream>>>(Whh1f, Whh1b, xwf, xwb, hc2, hpp);

    classifier_k<<<2048, 256, 0, stream>>>(hc2, truth, tf, Wc, bc, out);
}

// Round 12
// 4103.012 us; speedup vs baseline: 1.0159x; 1.0159x over previous
//
#include <hip/hip_runtime.h>

// ---------------------------------------------------------------------------
// LSTM_NER_TeacherForcing: B=32, T=512, E=512, H=512, V=50000, C=32, L=2
// embed -> [mfma gemm xw -> persistent scan] x2 -> classifier
// Round 12 (scan, R9 base): recombination of proven pieces.
//   - predicated re-poll WITH s_sleep(1) backoff (R11 showed sleep-free spin
//     congests the coherence point and delays producer stores: 1.25->1.84ms);
//   - xw one-step register prefetch issued post-stage (removes xw HBM miss
//     from the FIFO-serialized poll-wait chain);
//   - grid 256 blocks x 256 thr, everything else exactly R9.
// ---------------------------------------------------------------------------

#define BB 32
#define TT 512
#define EE 512
#define HH 512
#define NG 2048   // 4*H gate rows
#define CC 32

typedef __attribute__((ext_vector_type(8))) short short8v;
typedef __attribute__((ext_vector_type(4))) float float4v;
typedef unsigned long long u64;

__device__ __forceinline__ float bf2f(unsigned short u) {
    return __uint_as_float(((unsigned)u) << 16);
}
__device__ __forceinline__ float bf_lo(unsigned u) { return __uint_as_float(u << 16); }
__device__ __forceinline__ float bf_hi(unsigned u) { return __uint_as_float(u & 0xffff0000u); }
__device__ __forceinline__ unsigned short f2bf(float f) {
    unsigned u = __float_as_uint(f);
    u += 0x7fffu + ((u >> 16) & 1u);   // RNE
    return (unsigned short)(u >> 16);
}
__device__ __forceinline__ unsigned pk2(float a, float b) {
    return (unsigned)f2bf(a) | ((unsigned)f2bf(b) << 16);
}
__device__ __forceinline__ float fast_sigmoid(float x) {
    return 1.f / (1.f + __expf(-x));
}
__device__ __forceinline__ float fast_tanh(float x) {
    x = fminf(fmaxf(x, -15.f), 15.f);
    float e = __expf(2.f * x);
    return (e - 1.f) / (e + 1.f);
}

// ---------------------------------------------------------------------------
// 1) Embedding gather: h0[b,t,e] = emb[x[b,t]][e]  (f32 -> bf16)
__global__ __launch_bounds__(256)
void embed_k(const int* __restrict__ x, const float* __restrict__ emb,
             unsigned short* __restrict__ h0) {
    int idx = blockIdx.x * 256 + threadIdx.x;    // one float4 each
    int row = idx >> 7;                          // E/4 = 128 chunks per row
    int c4  = idx & 127;
    int tok = x[row];
    float4 v = *(const float4*)(emb + ((size_t)tok << 9) + (c4 << 2));
    ushort4 o;
    o.x = f2bf(v.x); o.y = f2bf(v.y); o.z = f2bf(v.z); o.w = f2bf(v.w);
    *(ushort4*)(h0 + ((size_t)row << 9) + (c4 << 2)) = o;
}

// ---------------------------------------------------------------------------
// 2) Input GEMM via MFMA. 128x128 tile, BK=64, 512 thr (8 waves, 2x4 grid,
// each wave 64x32 = 4x2 16x16 frags). LDS rows 128B, XOR-swizzled (r&7)<<4.
// Output PERMUTED: xwp[((jb*512+t)*32+b)*64 + gate*16+jj] (normal stores).
__global__ __launch_bounds__(512)
void gemm_xw(const unsigned short* __restrict__ A, const float* __restrict__ Bw,
             const float* __restrict__ bih, const float* __restrict__ bhh,
             unsigned short* __restrict__ Cp, int M, int K) {
    __shared__ __align__(16) unsigned char As[128 * 128];  // 128 rows x 64 bf16
    __shared__ __align__(16) unsigned char Bs[128 * 128];
    const int bn = blockIdx.x & 15, bm = blockIdx.x >> 4;
    const int tid = threadIdx.x;
    const int wv = tid >> 6, lane = tid & 63;
    const int wr = wv >> 2, wc = wv & 3;          // wave tile: rows wr*64, cols wc*32
    const int srow = tid >> 2, skc = (tid & 3) * 16;   // staging: row, bf16-chunk
    const unsigned sswz = (srow & 7) << 4;
    const int fr = lane & 15, fkb = (lane >> 4) * 16;  // frag row, k-byte base

    float4v acc[4][2];
#pragma unroll
    for (int i = 0; i < 4; ++i) { acc[i][0] = (float4v)(0.f); acc[i][1] = (float4v)(0.f); }

    const unsigned short* arow_p = A + (size_t)(bm * 128 + srow) * K + skc;
    const float* brow_p = Bw + (size_t)(bn * 128 + srow) * K + skc;
    unsigned char* const as_row = As + srow * 128;
    unsigned char* const bs_row = Bs + srow * 128;
    const int sb0 = skc * 2;

    for (int k0 = 0; k0 < K; k0 += 64) {
        // stage A: 16 bf16 (2x uint4)
        uint4 a0 = *(const uint4*)(arow_p + k0);
        uint4 a1 = *(const uint4*)(arow_p + k0 + 8);
        // stage B: 16 f32 -> 16 bf16
        float4 b0 = *(const float4*)(brow_p + k0);
        float4 b1 = *(const float4*)(brow_p + k0 + 4);
        float4 b2 = *(const float4*)(brow_p + k0 + 8);
        float4 b3 = *(const float4*)(brow_p + k0 + 12);
        *(uint4*)(as_row + ((sb0     ) ^ sswz)) = a0;
        *(uint4*)(as_row + ((sb0 + 16) ^ sswz)) = a1;
        uint4 bp0 = make_uint4(pk2(b0.x, b0.y), pk2(b0.z, b0.w), pk2(b1.x, b1.y), pk2(b1.z, b1.w));
        uint4 bp1 = make_uint4(pk2(b2.x, b2.y), pk2(b2.z, b2.w), pk2(b3.x, b3.y), pk2(b3.z, b3.w));
        *(uint4*)(bs_row + ((sb0     ) ^ sswz)) = bp0;
        *(uint4*)(bs_row + ((sb0 + 16) ^ sswz)) = bp1;
        __syncthreads();

#pragma unroll
        for (int kt = 0; kt < 2; ++kt) {
            const int cb = kt * 64 + fkb;
            short8v af[4], bf[2];
#pragma unroll
            for (int mt = 0; mt < 4; ++mt) {
                const int r = wr * 64 + mt * 16 + fr;
                af[mt] = *(const short8v*)(As + r * 128 + (cb ^ ((r & 7) << 4)));
            }
#pragma unroll
            for (int nt = 0; nt < 2; ++nt) {
                const int r = wc * 32 + nt * 16 + fr;
                bf[nt] = *(const short8v*)(Bs + r * 128 + (cb ^ ((r & 7) << 4)));
            }
#pragma unroll
            for (int mt = 0; mt < 4; ++mt) {
                acc[mt][0] = __builtin_amdgcn_mfma_f32_16x16x32_bf16(af[mt], bf[0], acc[mt][0], 0, 0, 0);
                acc[mt][1] = __builtin_amdgcn_mfma_f32_16x16x32_bf16(af[mt], bf[1], acc[mt][1], 0, 0, 0);
            }
        }
        __syncthreads();
    }

    const int r4 = (lane >> 4) * 4;
#pragma unroll
    for (int nt = 0; nt < 2; ++nt) {
        const int nglob = bn * 128 + wc * 32 + nt * 16 + fr;
        const float bias = bih[nglob] + bhh[nglob];
        const int gate = nglob >> 9;
        const int jbv = (nglob & 511) >> 4;
        const int loc = gate * 16 + (nglob & 15);
#pragma unroll
        for (int mt = 0; mt < 4; ++mt) {
#pragma unroll
            for (int i = 0; i < 4; ++i) {
                const int mglob = bm * 128 + wr * 64 + mt * 16 + r4 + i;
                const int b = mglob >> 9, t = mglob & 511;
                Cp[(((size_t)jbv * 512 + t) * 32 + b) * 64 + loc] =
                    f2bf(acc[mt][nt][i] + bias);
            }
        }
    }
}

// ---------------------------------------------------------------------------
// 3) Persistent bidirectional LSTM scan. grid = 256 blocks, 256 thr (4 waves).
// grp = blk&7 (dir*4+bg), jb = blk>>3. Wave w = gate type w (Whh in VGPRs).
// h crosses blocks as 64-bit {seq|2xbf16} packets, relaxed agent atomics,
// 4-slot rotation; predicated re-poll WITH s_sleep(1); xw reg-prefetch 1 step.
__global__ __launch_bounds__(256, 1)
void lstm_scan(const float* __restrict__ WhhF, const float* __restrict__ WhhB,
               const unsigned short* __restrict__ xwF, const unsigned short* __restrict__ xwB,
               unsigned short* __restrict__ outcat,   // (B,T,1024) bf16
               u64* __restrict__ h_pp) {              // [(slot*2+dir)*32+b][256] u64
    __shared__ __align__(16) unsigned char hs[16384];  // bf16 [16 rows][512 k], swizzled
    __shared__ float gsh[4][8][16];
    __shared__ unsigned xsh[2][256];

    const int blk = blockIdx.x;
    const int grp = blk & 7, jb = blk >> 3;
    const int bg = grp & 3, dir = grp >> 2;
    const int tid = threadIdx.x;
    const int wv = tid >> 6, lane = tid & 63;
    const float* Whh = dir ? WhhB : WhhF;
    const unsigned short* xw = dir ? xwB : xwF;
    const int js = jb << 4;

    // ---- preload weights into registers: wave wv = gate type wv ----
    short8v bw[16];
    {
        const float* wrow = Whh + (size_t)(wv * 512 + js + (lane & 15)) * HH
                            + (lane >> 4) * 8;
#pragma unroll
        for (int kk = 0; kk < 16; ++kk) {
            const float4 f0 = *(const float4*)(wrow + kk * 32);
            const float4 f1 = *(const float4*)(wrow + kk * 32 + 4);
            short8v b;
            b[0] = (short)f2bf(f0.x); b[1] = (short)f2bf(f0.y);
            b[2] = (short)f2bf(f0.z); b[3] = (short)f2bf(f0.w);
            b[4] = (short)f2bf(f1.x); b[5] = (short)f2bf(f1.y);
            b[6] = (short)f2bf(f1.z); b[7] = (short)f2bf(f1.w);
            bw[kk] = b;
        }
    }

    // zero hs rows 8..15 once (A-frag rows 8-15 are never re-written)
    for (int i = tid; i < 8 * 64; i += 256) {
        int r = 8 + (i >> 6), c = i & 63;
        *(uint4*)(hs + r * 1024 + ((c * 16) ^ ((r & 7) << 4))) = make_uint4(0, 0, 0, 0);
    }

    float c_st = 0.f;
    // stage coords: thread -> row tid>>5 (0..7), k-lane tid&31
    const int srow = tid >> 5, kcol = tid & 31;
    const unsigned swz_w = (srow & 7) << 4;
    // A-frag read coords
    const int arow = lane & 15, ag16 = (lane >> 4) * 16;
    const unsigned swz_r = (arow & 7) << 4;
    __syncthreads();

    // prime the xw register pipeline
    unsigned xv_cur = *(const unsigned*)(
        xw + (((size_t)jb * 512 + (dir ? TT - 1 : 0)) * 32 + bg * 8) * 64 + 2 * tid);
    unsigned xv_next = 0;

    for (int t = 0; t < TT; ++t) {
        const int tt = dir ? (TT - 1 - t) : t;

        // ---- stage h: predicated poll with sleep backoff until seq==t ----
        {
            const u64* hsrc =
                h_pp + ((size_t)((t & 3) * 2 + dir) * BB + bg * 8 + srow) * 256;
            const unsigned sq = (unsigned)t;
            u64 v0 = __hip_atomic_load(hsrc + kcol,       __ATOMIC_RELAXED, __HIP_MEMORY_SCOPE_AGENT);
            u64 v1 = __hip_atomic_load(hsrc + kcol + 32,  __ATOMIC_RELAXED, __HIP_MEMORY_SCOPE_AGENT);
            u64 v2 = __hip_atomic_load(hsrc + kcol + 64,  __ATOMIC_RELAXED, __HIP_MEMORY_SCOPE_AGENT);
            u64 v3 = __hip_atomic_load(hsrc + kcol + 96,  __ATOMIC_RELAXED, __HIP_MEMORY_SCOPE_AGENT);
            u64 v4 = __hip_atomic_load(hsrc + kcol + 128, __ATOMIC_RELAXED, __HIP_MEMORY_SCOPE_AGENT);
            u64 v5 = __hip_atomic_load(hsrc + kcol + 160, __ATOMIC_RELAXED, __HIP_MEMORY_SCOPE_AGENT);
            u64 v6 = __hip_atomic_load(hsrc + kcol + 192, __ATOMIC_RELAXED, __HIP_MEMORY_SCOPE_AGENT);
            u64 v7 = __hip_atomic_load(hsrc + kcol + 224, __ATOMIC_RELAXED, __HIP_MEMORY_SCOPE_AGENT);
            bool k0 = (unsigned)(v0 >> 32) == sq, k1 = (unsigned)(v1 >> 32) == sq;
            bool k2 = (unsigned)(v2 >> 32) == sq, k3 = (unsigned)(v3 >> 32) == sq;
            bool k4 = (unsigned)(v4 >> 32) == sq, k5 = (unsigned)(v5 >> 32) == sq;
            bool k6 = (unsigned)(v6 >> 32) == sq, k7 = (unsigned)(v7 >> 32) == sq;
            while (!(k0 && k1 && k2 && k3 && k4 && k5 && k6 && k7)) {
                __builtin_amdgcn_s_sleep(1);
                if (!k0) { v0 = __hip_atomic_load(hsrc + kcol,       __ATOMIC_RELAXED, __HIP_MEMORY_SCOPE_AGENT); k0 = (unsigned)(v0 >> 32) == sq; }
                if (!k1) { v1 = __hip_atomic_load(hsrc + kcol + 32,  __ATOMIC_RELAXED, __HIP_MEMORY_SCOPE_AGENT); k1 = (unsigned)(v1 >> 32) == sq; }
                if (!k2) { v2 = __hip_atomic_load(hsrc + kcol + 64,  __ATOMIC_RELAXED, __HIP_MEMORY_SCOPE_AGENT); k2 = (unsigned)(v2 >> 32) == sq; }
                if (!k3) { v3 = __hip_atomic_load(hsrc + kcol + 96,  __ATOMIC_RELAXED, __HIP_MEMORY_SCOPE_AGENT); k3 = (unsigned)(v3 >> 32) == sq; }
                if (!k4) { v4 = __hip_atomic_load(hsrc + kcol + 128, __ATOMIC_RELAXED, __HIP_MEMORY_SCOPE_AGENT); k4 = (unsigned)(v4 >> 32) == sq; }
                if (!k5) { v5 = __hip_atomic_load(hsrc + kcol + 160, __ATOMIC_RELAXED, __HIP_MEMORY_SCOPE_AGENT); k5 = (unsigned)(v5 >> 32) == sq; }
                if (!k6) { v6 = __hip_atomic_load(hsrc + kcol + 192, __ATOMIC_RELAXED, __HIP_MEMORY_SCOPE_AGENT); k6 = (unsigned)(v6 >> 32) == sq; }
                if (!k7) { v7 = __hip_atomic_load(hsrc + kcol + 224, __ATOMIC_RELAXED, __HIP_MEMORY_SCOPE_AGENT); k7 = (unsigned)(v7 >> 32) == sq; }
            }
            xsh[t & 1][tid] = xv_cur;
            unsigned char* hrow = hs + srow * 1024;
            *(unsigned*)(hrow + ((4 * kcol +   0) ^ swz_w)) = (unsigned)v0;
            *(unsigned*)(hrow + ((4 * kcol + 128) ^ swz_w)) = (unsigned)v1;
            *(unsigned*)(hrow + ((4 * kcol + 256) ^ swz_w)) = (unsigned)v2;
            *(unsigned*)(hrow + ((4 * kcol + 384) ^ swz_w)) = (unsigned)v3;
            *(unsigned*)(hrow + ((4 * kcol + 512) ^ swz_w)) = (unsigned)v4;
            *(unsigned*)(hrow + ((4 * kcol + 640) ^ swz_w)) = (unsigned)v5;
            *(unsigned*)(hrow + ((4 * kcol + 768) ^ swz_w)) = (unsigned)v6;
            *(unsigned*)(hrow + ((4 * kcol + 896) ^ swz_w)) = (unsigned)v7;
        }
        // prefetch next step's xw into a register (not in the poll-wait chain)
        if (t + 1 < TT) {
            const int ttn = dir ? (TT - 2 - t) : (t + 1);
            xv_next = *(const unsigned*)(
                xw + (((size_t)jb * 512 + ttn) * 32 + bg * 8) * 64 + 2 * tid);
        }
        __syncthreads();   // (1) h staged + xsh written

        // ---- MFMA: wave wv computes gates[wv][b 0..7][jj 0..15] over K=512 ----
        {
            float4v a0 = (float4v)(0.0f), a1 = (float4v)(0.0f);
#pragma unroll
            for (int kk = 0; kk < 16; kk += 2) {
                short8v af0 = *(const short8v*)(hs + arow * 1024 +
                                  (((kk * 64) + ag16) ^ swz_r));
                short8v af1 = *(const short8v*)(hs + arow * 1024 +
                                  ((((kk + 1) * 64) + ag16) ^ swz_r));
                a0 = __builtin_amdgcn_mfma_f32_16x16x32_bf16(af0, bw[kk], a0, 0, 0, 0);
                a1 = __builtin_amdgcn_mfma_f32_16x16x32_bf16(af1, bw[kk + 1], a1, 0, 0, 0);
            }
            if (lane < 32) {   // rows 0..7 valid: row=(lane>>4)*4+reg, col=lane&15
#pragma unroll
                for (int reg = 0; reg < 4; ++reg) {
                    gsh[wv][(lane >> 4) * 4 + reg][lane & 15] = a0[reg] + a1[reg];
                }
            }
        }
        __syncthreads();   // (2) gates in gsh

        // ---- gate nonlinearity + state update (tid<128: b=tid>>4, jj=tid&15) ----
        if (tid < 128) {
            const int bl = tid >> 4, jj = tid & 15;
            const unsigned short* xp = (const unsigned short*)xsh[t & 1];
            const int vb = bl * 64 + jj;
            float gi = gsh[0][bl][jj] + bf2f(xp[vb]);
            float gf = gsh[1][bl][jj] + bf2f(xp[vb + 16]);
            float gg = gsh[2][bl][jj] + bf2f(xp[vb + 32]);
            float go = gsh[3][bl][jj] + bf2f(xp[vb + 48]);
            float si = fast_sigmoid(gi);
            float sf = fast_sigmoid(gf);
            float so = fast_sigmoid(go);
            c_st = sf * c_st + si * fast_tanh(gg);
            float hv = so * fast_tanh(c_st);
            const unsigned short hb16 = f2bf(hv);
            const int b_glob = bg * 8 + bl;
            // pack pair (jj even|odd) + seq into one 64-bit packet
            unsigned hv32 = hb16;
            unsigned other = (unsigned)__shfl_xor((int)hv32, 1);
            if (!(tid & 1)) {
                u64 pkt = ((u64)(unsigned)(t + 1) << 32) | (u64)(hv32 | (other << 16));
                __hip_atomic_store(
                    &h_pp[((size_t)(((t + 1) & 3) * 2 + dir) * BB + b_glob) * 256
                          + jb * 8 + (jj >> 1)],
                    pkt, __ATOMIC_RELAXED, __HIP_MEMORY_SCOPE_AGENT);
            }
            outcat[((size_t)b_glob * TT + tt) * 1024 + dir * HH + js + jj] = hb16;
        }
        xv_cur = xv_next;
        // no third barrier: xsh is double-buffered; hs/gsh protected by (1),(2)
    }
}

// ---------------------------------------------------------------------------
// 4) Classifier + log_softmax, transposed write (B,C,T).
__global__ __launch_bounds__(256)
void classifier_k(const unsigned short* __restrict__ hcat, const float* __restrict__ truth,
                  const int* __restrict__ tf, const float* __restrict__ Wc,
                  const float* __restrict__ bc, float* __restrict__ out) {
    __shared__ float feat[8][1024];
    __shared__ float featp[8];
    const int tid = threadIdx.x;
    const int bt0 = blockIdx.x * 8;
    for (int i = tid; i < 8 * 128; i += 256) {   // 8 rows x 128 chunks(8 vals)
        int bl = i >> 7, ch = i & 127;
        uint4 u = *(const uint4*)(hcat + (size_t)(bt0 + bl) * 1024 + ch * 8);
        *(float4*)&feat[bl][ch * 8] = make_float4(bf_lo(u.x), bf_hi(u.x), bf_lo(u.y), bf_hi(u.y));
        *(float4*)&feat[bl][ch * 8 + 4] = make_float4(bf_lo(u.z), bf_hi(u.z), bf_lo(u.w), bf_hi(u.w));
    }
    if (tid < 8) {
        int bt = bt0 + tid;
        int t = bt & 511;
        featp[tid] = (t > 0 && tf[0] != 0) ? truth[bt - 1] : 0.f;
    }
    __syncthreads();
    const int bl = tid >> 5, c = tid & 31;
    const int bt = bt0 + bl;
    float acc = featp[bl] * Wc[c * 1025] + bc[c];
    const float* w = Wc + c * 1025 + 1;
    for (int f4 = 0; f4 < 256; ++f4) {
        const float4 fv = *(const float4*)&feat[bl][f4 * 4];
        acc = fmaf(fv.x, w[f4 * 4 + 0],
              fmaf(fv.y, w[f4 * 4 + 1],
              fmaf(fv.z, w[f4 * 4 + 2],
              fmaf(fv.w, w[f4 * 4 + 3], acc))));
    }
    float m = acc;
#pragma unroll
    for (int mk = 16; mk; mk >>= 1) m = fmaxf(m, __shfl_xor(m, mk));
    float e = expf(acc - m);
    float s = e;
#pragma unroll
    for (int mk = 16; mk; mk >>= 1) s += __shfl_xor(s, mk);
    float lse = m + logf(s);
    int b = bt >> 9, t = bt & 511;
    out[((size_t)b * CC + c) * TT + t] = acc - lse;
}

// ---------------------------------------------------------------------------
extern "C" void kernel_launch(void* const* d_in, const int* in_sizes, int n_in,
                              void* d_out, int out_size, void* d_ws, size_t ws_size,
                              hipStream_t stream) {
    const int* x = (const int*)d_in[0];
    const float* truth = (const float*)d_in[1];
    const int* tf = (const int*)d_in[2];
    const float* emb = (const float*)d_in[3];
    const float* Wih0f = (const float*)d_in[4];
    const float* Whh0f = (const float*)d_in[5];
    const float* bih0f = (const float*)d_in[6];
    const float* bhh0f = (const float*)d_in[7];
    const float* Wih0b = (const float*)d_in[8];
    const float* Whh0b = (const float*)d_in[9];
    const float* bih0b = (const float*)d_in[10];
    const float* bhh0b = (const float*)d_in[11];
    const float* Wih1f = (const float*)d_in[12];
    const float* Whh1f = (const float*)d_in[13];
    const float* bih1f = (const float*)d_in[14];
    const float* bhh1f = (const float*)d_in[15];
    const float* Wih1b = (const float*)d_in[16];
    const float* Whh1b = (const float*)d_in[17];
    const float* bih1b = (const float*)d_in[18];
    const float* bhh1b = (const float*)d_in[19];
    const float* Wc = (const float*)d_in[20];
    const float* bc = (const float*)d_in[21];
    float* out = (float*)d_out;

    // ws layout (bytes)
    const size_t off_h0  = 0;                       // (B,T,512) bf16 : 16 MB
    const size_t off_xwf = 16777216;                // perm (32,512,32,64) bf16: 64 MB
    const size_t off_xwb = off_xwf + 67108864;
    const size_t off_hc1 = off_xwb + 67108864;      // (B,T,1024) bf16: 32 MB
    const size_t off_hc2 = off_hc1 + 33554432;
    const size_t off_hpp = off_hc2 + 33554432;      // u64 packets: 4*2*32*256*8 = 512 KB
    const size_t need = off_hpp + 524288;
    if (ws_size < need) return;

    char* ws = (char*)d_ws;
    unsigned short* h0  = (unsigned short*)(ws + off_h0);
    unsigned short* xwf = (unsigned short*)(ws + off_xwf);
    unsigned short* xwb = (unsigned short*)(ws + off_xwb);
    unsigned short* hc1 = (unsigned short*)(ws + off_hc1);
    unsigned short* hc2 = (unsigned short*)(ws + off_hc2);
    u64*            hpp = (u64*)(ws + off_hpp);

    embed_k<<<8192, 256, 0, stream>>>(x, emb, h0);

    // layer 0
    gemm_xw<<<2048, 512, 0, stream>>>(h0, Wih0f, bih0f, bhh0f, xwf, BB * TT, EE);
    gemm_xw<<<2048, 512, 0, stream>>>(h0, Wih0b, bih0b, bhh0b, xwb, BB * TT, EE);
    (void)hipMemsetAsync(ws + off_hpp, 0, 524288, stream);
    lstm_scan<<<256, 256, 0, stream>>>(Whh0f, Whh0b, xwf, xwb, hc1, hpp);

    // layer 1
    gemm_xw<<<2048, 512, 0, stream>>>(hc1, Wih1f, bih1f, bhh1f, xwf, BB * TT, 1024);
    gemm_xw<<<2048, 512, 0, stream>>>(hc1, Wih1b, bih1b, bhh1b, xwb, BB * TT, 1024);
    (void)hipMemsetAsync(ws + off_hpp, 0, 524288, stream);
    lstm_scan<<<256, 256, 0, stream>>>(Whh1f, Whh1b, xwf, xwb, hc2, hpp);

    classifier_k<<<2048, 256, 0, stream>>>(hc2, truth, tf, Wc, bc, out);
}

// Round 13
// 3158.687 us; speedup vs baseline: 1.3196x; 1.2990x over previous
//
#include <hip/hip_runtime.h>

// ---------------------------------------------------------------------------
// LSTM_NER_TeacherForcing: B=32, T=512, E=512, H=512, V=50000, C=32, L=2
// embed -> [mfma gemm xw -> persistent scan] x2 -> classifier
// Round 13: REVERT to exact Round-9 kernel (best measured: 3.16 ms).
// Ablation summary (scan per-dispatch): R9 full-reload+sleep poll = 1.25 ms;
// predicated+sleep = 1.32-1.74; predicated no-sleep = 1.84; NT hints = 1.43.
// R9's poll wins on memory-level parallelism: 8 packet loads in flight per
// round, single waitcnt -> one fabric RT per sampling round.
// ---------------------------------------------------------------------------

#define BB 32
#define TT 512
#define EE 512
#define HH 512
#define NG 2048   // 4*H gate rows
#define CC 32

typedef __attribute__((ext_vector_type(8))) short short8v;
typedef __attribute__((ext_vector_type(4))) float float4v;
typedef unsigned long long u64;

__device__ __forceinline__ float bf2f(unsigned short u) {
    return __uint_as_float(((unsigned)u) << 16);
}
__device__ __forceinline__ float bf_lo(unsigned u) { return __uint_as_float(u << 16); }
__device__ __forceinline__ float bf_hi(unsigned u) { return __uint_as_float(u & 0xffff0000u); }
__device__ __forceinline__ unsigned short f2bf(float f) {
    unsigned u = __float_as_uint(f);
    u += 0x7fffu + ((u >> 16) & 1u);   // RNE
    return (unsigned short)(u >> 16);
}
__device__ __forceinline__ unsigned pk2(float a, float b) {
    return (unsigned)f2bf(a) | ((unsigned)f2bf(b) << 16);
}
__device__ __forceinline__ float fast_sigmoid(float x) {
    return 1.f / (1.f + __expf(-x));
}
__device__ __forceinline__ float fast_tanh(float x) {
    x = fminf(fmaxf(x, -15.f), 15.f);
    float e = __expf(2.f * x);
    return (e - 1.f) / (e + 1.f);
}

// ---------------------------------------------------------------------------
// 1) Embedding gather: h0[b,t,e] = emb[x[b,t]][e]  (f32 -> bf16)
__global__ __launch_bounds__(256)
void embed_k(const int* __restrict__ x, const float* __restrict__ emb,
             unsigned short* __restrict__ h0) {
    int idx = blockIdx.x * 256 + threadIdx.x;    // one float4 each
    int row = idx >> 7;                          // E/4 = 128 chunks per row
    int c4  = idx & 127;
    int tok = x[row];
    float4 v = *(const float4*)(emb + ((size_t)tok << 9) + (c4 << 2));
    ushort4 o;
    o.x = f2bf(v.x); o.y = f2bf(v.y); o.z = f2bf(v.z); o.w = f2bf(v.w);
    *(ushort4*)(h0 + ((size_t)row << 9) + (c4 << 2)) = o;
}

// ---------------------------------------------------------------------------
// 2) Input GEMM via MFMA. 128x128 tile, BK=64, 512 thr (8 waves, 2x4 grid,
// each wave 64x32 = 4x2 16x16 frags). LDS rows 128B, XOR-swizzled (r&7)<<4.
// Output PERMUTED: xwp[((jb*512+t)*32+b)*64 + gate*16+jj] (normal stores).
__global__ __launch_bounds__(512)
void gemm_xw(const unsigned short* __restrict__ A, const float* __restrict__ Bw,
             const float* __restrict__ bih, const float* __restrict__ bhh,
             unsigned short* __restrict__ Cp, int M, int K) {
    __shared__ __align__(16) unsigned char As[128 * 128];  // 128 rows x 64 bf16
    __shared__ __align__(16) unsigned char Bs[128 * 128];
    const int bn = blockIdx.x & 15, bm = blockIdx.x >> 4;
    const int tid = threadIdx.x;
    const int wv = tid >> 6, lane = tid & 63;
    const int wr = wv >> 2, wc = wv & 3;          // wave tile: rows wr*64, cols wc*32
    const int srow = tid >> 2, skc = (tid & 3) * 16;   // staging: row, bf16-chunk
    const unsigned sswz = (srow & 7) << 4;
    const int fr = lane & 15, fkb = (lane >> 4) * 16;  // frag row, k-byte base

    float4v acc[4][2];
#pragma unroll
    for (int i = 0; i < 4; ++i) { acc[i][0] = (float4v)(0.f); acc[i][1] = (float4v)(0.f); }

    const unsigned short* arow_p = A + (size_t)(bm * 128 + srow) * K + skc;
    const float* brow_p = Bw + (size_t)(bn * 128 + srow) * K + skc;
    unsigned char* const as_row = As + srow * 128;
    unsigned char* const bs_row = Bs + srow * 128;
    const int sb0 = skc * 2;

    for (int k0 = 0; k0 < K; k0 += 64) {
        // stage A: 16 bf16 (2x uint4)
        uint4 a0 = *(const uint4*)(arow_p + k0);
        uint4 a1 = *(const uint4*)(arow_p + k0 + 8);
        // stage B: 16 f32 -> 16 bf16
        float4 b0 = *(const float4*)(brow_p + k0);
        float4 b1 = *(const float4*)(brow_p + k0 + 4);
        float4 b2 = *(const float4*)(brow_p + k0 + 8);
        float4 b3 = *(const float4*)(brow_p + k0 + 12);
        *(uint4*)(as_row + ((sb0     ) ^ sswz)) = a0;
        *(uint4*)(as_row + ((sb0 + 16) ^ sswz)) = a1;
        uint4 bp0 = make_uint4(pk2(b0.x, b0.y), pk2(b0.z, b0.w), pk2(b1.x, b1.y), pk2(b1.z, b1.w));
        uint4 bp1 = make_uint4(pk2(b2.x, b2.y), pk2(b2.z, b2.w), pk2(b3.x, b3.y), pk2(b3.z, b3.w));
        *(uint4*)(bs_row + ((sb0     ) ^ sswz)) = bp0;
        *(uint4*)(bs_row + ((sb0 + 16) ^ sswz)) = bp1;
        __syncthreads();

#pragma unroll
        for (int kt = 0; kt < 2; ++kt) {
            const int cb = kt * 64 + fkb;
            short8v af[4], bf[2];
#pragma unroll
            for (int mt = 0; mt < 4; ++mt) {
                const int r = wr * 64 + mt * 16 + fr;
                af[mt] = *(const short8v*)(As + r * 128 + (cb ^ ((r & 7) << 4)));
            }
#pragma unroll
            for (int nt = 0; nt < 2; ++nt) {
                const int r = wc * 32 + nt * 16 + fr;
                bf[nt] = *(const short8v*)(Bs + r * 128 + (cb ^ ((r & 7) << 4)));
            }
#pragma unroll
            for (int mt = 0; mt < 4; ++mt) {
                acc[mt][0] = __builtin_amdgcn_mfma_f32_16x16x32_bf16(af[mt], bf[0], acc[mt][0], 0, 0, 0);
                acc[mt][1] = __builtin_amdgcn_mfma_f32_16x16x32_bf16(af[mt], bf[1], acc[mt][1], 0, 0, 0);
            }
        }
        __syncthreads();
    }

    const int r4 = (lane >> 4) * 4;
#pragma unroll
    for (int nt = 0; nt < 2; ++nt) {
        const int nglob = bn * 128 + wc * 32 + nt * 16 + fr;
        const float bias = bih[nglob] + bhh[nglob];
        const int gate = nglob >> 9;
        const int jbv = (nglob & 511) >> 4;
        const int loc = gate * 16 + (nglob & 15);
#pragma unroll
        for (int mt = 0; mt < 4; ++mt) {
#pragma unroll
            for (int i = 0; i < 4; ++i) {
                const int mglob = bm * 128 + wr * 64 + mt * 16 + r4 + i;
                const int b = mglob >> 9, t = mglob & 511;
                Cp[(((size_t)jbv * 512 + t) * 32 + b) * 64 + loc] =
                    f2bf(acc[mt][nt][i] + bias);
            }
        }
    }
}

// ---------------------------------------------------------------------------
// 3) Persistent bidirectional LSTM scan (Round-7/9 version, best measured).
// grid = 256 blocks, 256 thr (4 waves). grp = blk&7, jb = blk>>3.
// Wave w = gate type w (Whh rows in VGPRs). h crosses blocks as 64-bit
// {seq|2xbf16} packets, relaxed agent atomics, 4-slot rotation, data-polled
// (full 8-packet reload per round: max MLP, one fabric RT per sampling round).
__global__ __launch_bounds__(256, 1)
void lstm_scan(const float* __restrict__ WhhF, const float* __restrict__ WhhB,
               const unsigned short* __restrict__ xwF, const unsigned short* __restrict__ xwB,
               unsigned short* __restrict__ outcat,   // (B,T,1024) bf16
               u64* __restrict__ h_pp) {              // [(slot*2+dir)*32+b][256] u64
    __shared__ __align__(16) unsigned char hs[16384];  // bf16 [16 rows][512 k], swizzled
    __shared__ float gsh[4][8][16];
    __shared__ unsigned xsh[2][256];

    const int blk = blockIdx.x;
    const int grp = blk & 7, jb = blk >> 3;
    const int bg = grp & 3, dir = grp >> 2;
    const int tid = threadIdx.x;
    const int wv = tid >> 6, lane = tid & 63;
    const float* Whh = dir ? WhhB : WhhF;
    const unsigned short* xw = dir ? xwB : xwF;
    const int js = jb << 4;

    // ---- preload weights into registers: wave wv = gate type wv ----
    short8v bw[16];
    {
        const float* wrow = Whh + (size_t)(wv * 512 + js + (lane & 15)) * HH
                            + (lane >> 4) * 8;
#pragma unroll
        for (int kk = 0; kk < 16; ++kk) {
            const float4 f0 = *(const float4*)(wrow + kk * 32);
            const float4 f1 = *(const float4*)(wrow + kk * 32 + 4);
            short8v b;
            b[0] = (short)f2bf(f0.x); b[1] = (short)f2bf(f0.y);
            b[2] = (short)f2bf(f0.z); b[3] = (short)f2bf(f0.w);
            b[4] = (short)f2bf(f1.x); b[5] = (short)f2bf(f1.y);
            b[6] = (short)f2bf(f1.z); b[7] = (short)f2bf(f1.w);
            bw[kk] = b;
        }
    }

    // zero hs rows 8..15 once (A-frag rows 8-15 are never re-written)
    for (int i = tid; i < 8 * 64; i += 256) {
        int r = 8 + (i >> 6), c = i & 63;
        *(uint4*)(hs + r * 1024 + ((c * 16) ^ ((r & 7) << 4))) = make_uint4(0, 0, 0, 0);
    }

    float c_st = 0.f;
    // stage coords: thread -> row tid>>5 (0..7), k-lane tid&31
    const int srow = tid >> 5, kcol = tid & 31;
    const unsigned swz_w = (srow & 7) << 4;
    // A-frag read coords
    const int arow = lane & 15, ag16 = (lane >> 4) * 16;
    const unsigned swz_r = (arow & 7) << 4;
    __syncthreads();

    for (int t = 0; t < TT; ++t) {
        const int tt = dir ? (TT - 1 - t) : t;

        // xw slice for this step (1KB contiguous), hoisted above the poll:
        // its HBM/L3 latency hides under the packet spin.
        const unsigned xv = *(const unsigned*)(
            xw + (((size_t)jb * 512 + tt) * 32 + bg * 8) * 64 + 2 * tid);

        // ---- stage h: poll self-validating packets until seq==t ----
        {
            const u64* hsrc =
                h_pp + ((size_t)((t & 3) * 2 + dir) * BB + bg * 8 + srow) * 256;
            const unsigned sq = (unsigned)t;
            u64 v0, v1, v2, v3, v4, v5, v6, v7;
            for (;;) {
                v0 = __hip_atomic_load(hsrc + kcol,       __ATOMIC_RELAXED, __HIP_MEMORY_SCOPE_AGENT);
                v1 = __hip_atomic_load(hsrc + kcol + 32,  __ATOMIC_RELAXED, __HIP_MEMORY_SCOPE_AGENT);
                v2 = __hip_atomic_load(hsrc + kcol + 64,  __ATOMIC_RELAXED, __HIP_MEMORY_SCOPE_AGENT);
                v3 = __hip_atomic_load(hsrc + kcol + 96,  __ATOMIC_RELAXED, __HIP_MEMORY_SCOPE_AGENT);
                v4 = __hip_atomic_load(hsrc + kcol + 128, __ATOMIC_RELAXED, __HIP_MEMORY_SCOPE_AGENT);
                v5 = __hip_atomic_load(hsrc + kcol + 160, __ATOMIC_RELAXED, __HIP_MEMORY_SCOPE_AGENT);
                v6 = __hip_atomic_load(hsrc + kcol + 192, __ATOMIC_RELAXED, __HIP_MEMORY_SCOPE_AGENT);
                v7 = __hip_atomic_load(hsrc + kcol + 224, __ATOMIC_RELAXED, __HIP_MEMORY_SCOPE_AGENT);
                unsigned ok = ((unsigned)(v0 >> 32) == sq) & ((unsigned)(v1 >> 32) == sq)
                            & ((unsigned)(v2 >> 32) == sq) & ((unsigned)(v3 >> 32) == sq)
                            & ((unsigned)(v4 >> 32) == sq) & ((unsigned)(v5 >> 32) == sq)
                            & ((unsigned)(v6 >> 32) == sq) & ((unsigned)(v7 >> 32) == sq);
                if (ok) break;
                __builtin_amdgcn_s_sleep(1);
            }
            xsh[t & 1][tid] = xv;
            unsigned char* hrow = hs + srow * 1024;
            *(unsigned*)(hrow + ((4 * kcol +   0) ^ swz_w)) = (unsigned)v0;
            *(unsigned*)(hrow + ((4 * kcol + 128) ^ swz_w)) = (unsigned)v1;
            *(unsigned*)(hrow + ((4 * kcol + 256) ^ swz_w)) = (unsigned)v2;
            *(unsigned*)(hrow + ((4 * kcol + 384) ^ swz_w)) = (unsigned)v3;
            *(unsigned*)(hrow + ((4 * kcol + 512) ^ swz_w)) = (unsigned)v4;
            *(unsigned*)(hrow + ((4 * kcol + 640) ^ swz_w)) = (unsigned)v5;
            *(unsigned*)(hrow + ((4 * kcol + 768) ^ swz_w)) = (unsigned)v6;
            *(unsigned*)(hrow + ((4 * kcol + 896) ^ swz_w)) = (unsigned)v7;
        }
        __syncthreads();   // (1) h staged + xsh written

        // ---- MFMA: wave wv computes gates[wv][b 0..7][jj 0..15] over K=512 ----
        {
            float4v a0 = (float4v)(0.0f), a1 = (float4v)(0.0f);
#pragma unroll
            for (int kk = 0; kk < 16; kk += 2) {
                short8v af0 = *(const short8v*)(hs + arow * 1024 +
                                  (((kk * 64) + ag16) ^ swz_r));
                short8v af1 = *(const short8v*)(hs + arow * 1024 +
                                  ((((kk + 1) * 64) + ag16) ^ swz_r));
                a0 = __builtin_amdgcn_mfma_f32_16x16x32_bf16(af0, bw[kk], a0, 0, 0, 0);
                a1 = __builtin_amdgcn_mfma_f32_16x16x32_bf16(af1, bw[kk + 1], a1, 0, 0, 0);
            }
            if (lane < 32) {   // rows 0..7 valid: row=(lane>>4)*4+reg, col=lane&15
#pragma unroll
                for (int reg = 0; reg < 4; ++reg) {
                    gsh[wv][(lane >> 4) * 4 + reg][lane & 15] = a0[reg] + a1[reg];
                }
            }
        }
        __syncthreads();   // (2) gates in gsh

        // ---- gate nonlinearity + state update (tid<128: b=tid>>4, jj=tid&15) ----
        if (tid < 128) {
            const int bl = tid >> 4, jj = tid & 15;
            const unsigned short* xp = (const unsigned short*)xsh[t & 1];
            const int vb = bl * 64 + jj;
            float gi = gsh[0][bl][jj] + bf2f(xp[vb]);
            float gf = gsh[1][bl][jj] + bf2f(xp[vb + 16]);
            float gg = gsh[2][bl][jj] + bf2f(xp[vb + 32]);
            float go = gsh[3][bl][jj] + bf2f(xp[vb + 48]);
            float si = fast_sigmoid(gi);
            float sf = fast_sigmoid(gf);
            float so = fast_sigmoid(go);
            c_st = sf * c_st + si * fast_tanh(gg);
            float hv = so * fast_tanh(c_st);
            const unsigned short hb16 = f2bf(hv);
            const int b_glob = bg * 8 + bl;
            // pack pair (jj even|odd) + seq into one 64-bit packet
            unsigned hv32 = hb16;
            unsigned other = (unsigned)__shfl_xor((int)hv32, 1);
            if (!(tid & 1)) {
                u64 pkt = ((u64)(unsigned)(t + 1) << 32) | (u64)(hv32 | (other << 16));
                __hip_atomic_store(
                    &h_pp[((size_t)(((t + 1) & 3) * 2 + dir) * BB + b_glob) * 256
                          + jb * 8 + (jj >> 1)],
                    pkt, __ATOMIC_RELAXED, __HIP_MEMORY_SCOPE_AGENT);
            }
            outcat[((size_t)b_glob * TT + tt) * 1024 + dir * HH + js + jj] = hb16;
        }
        // no third barrier: xsh is double-buffered; hs/gsh protected by (1),(2)
    }
}

// ---------------------------------------------------------------------------
// 4) Classifier + log_softmax, transposed write (B,C,T).
__global__ __launch_bounds__(256)
void classifier_k(const unsigned short* __restrict__ hcat, const float* __restrict__ truth,
                  const int* __restrict__ tf, const float* __restrict__ Wc,
                  const float* __restrict__ bc, float* __restrict__ out) {
    __shared__ float feat[8][1024];
    __shared__ float featp[8];
    const int tid = threadIdx.x;
    const int bt0 = blockIdx.x * 8;
    for (int i = tid; i < 8 * 128; i += 256) {   // 8 rows x 128 chunks(8 vals)
        int bl = i >> 7, ch = i & 127;
        uint4 u = *(const uint4*)(hcat + (size_t)(bt0 + bl) * 1024 + ch * 8);
        *(float4*)&feat[bl][ch * 8] = make_float4(bf_lo(u.x), bf_hi(u.x), bf_lo(u.y), bf_hi(u.y));
        *(float4*)&feat[bl][ch * 8 + 4] = make_float4(bf_lo(u.z), bf_hi(u.z), bf_lo(u.w), bf_hi(u.w));
    }
    if (tid < 8) {
        int bt = bt0 + tid;
        int t = bt & 511;
        featp[tid] = (t > 0 && tf[0] != 0) ? truth[bt - 1] : 0.f;
    }
    __syncthreads();
    const int bl = tid >> 5, c = tid & 31;
    const int bt = bt0 + bl;
    float acc = featp[bl] * Wc[c * 1025] + bc[c];
    const float* w = Wc + c * 1025 + 1;
    for (int f4 = 0; f4 < 256; ++f4) {
        const float4 fv = *(const float4*)&feat[bl][f4 * 4];
        acc = fmaf(fv.x, w[f4 * 4 + 0],
              fmaf(fv.y, w[f4 * 4 + 1],
              fmaf(fv.z, w[f4 * 4 + 2],
              fmaf(fv.w, w[f4 * 4 + 3], acc))));
    }
    float m = acc;
#pragma unroll
    for (int mk = 16; mk; mk >>= 1) m = fmaxf(m, __shfl_xor(m, mk));
    float e = expf(acc - m);
    float s = e;
#pragma unroll
    for (int mk = 16; mk; mk >>= 1) s += __shfl_xor(s, mk);
    float lse = m + logf(s);
    int b = bt >> 9, t = bt & 511;
    out[((size_t)b * CC + c) * TT + t] = acc - lse;
}

// ---------------------------------------------------------------------------
extern "C" void kernel_launch(void* const* d_in, const int* in_sizes, int n_in,
                              void* d_out, int out_size, void* d_ws, size_t ws_size,
                              hipStream_t stream) {
    const int* x = (const int*)d_in[0];
    const float* truth = (const float*)d_in[1];
    const int* tf = (const int*)d_in[2];
    const float* emb = (const float*)d_in[3];
    const float* Wih0f = (const float*)d_in[4];
    const float* Whh0f = (const float*)d_in[5];
    const float* bih0f = (const float*)d_in[6];
    const float* bhh0f = (const float*)d_in[7];
    const float* Wih0b = (const float*)d_in[8];
    const float* Whh0b = (const float*)d_in[9];
    const float* bih0b = (const float*)d_in[10];
    const float* bhh0b = (const float*)d_in[11];
    const float* Wih1f = (const float*)d_in[12];
    const float* Whh1f = (const float*)d_in[13];
    const float* bih1f = (const float*)d_in[14];
    const float* bhh1f = (const float*)d_in[15];
    const float* Wih1b = (const float*)d_in[16];
    const float* Whh1b = (const float*)d_in[17];
    const float* bih1b = (const float*)d_in[18];
    const float* bhh1b = (const float*)d_in[19];
    const float* Wc = (const float*)d_in[20];
    const float* bc = (const float*)d_in[21];
    float* out = (float*)d_out;

    // ws layout (bytes)
    const size_t off_h0  = 0;                       // (B,T,512) bf16 : 16 MB
    const size_t off_xwf = 16777216;                // perm (32,512,32,64) bf16: 64 MB
    const size_t off_xwb = off_xwf + 67108864;
    const size_t off_hc1 = off_xwb + 67108864;      // (B,T,1024) bf16: 32 MB
    const size_t off_hc2 = off_hc1 + 33554432;
    const size_t off_hpp = off_hc2 + 33554432;      // u64 packets: 4*2*32*256*8 = 512 KB
    const size_t need = off_hpp + 524288;
    if (ws_size < need) return;

    char* ws = (char*)d_ws;
    unsigned short* h0  = (unsigned short*)(ws + off_h0);
    unsigned short* xwf = (unsigned short*)(ws + off_xwf);
    unsigned short* xwb = (unsigned short*)(ws + off_xwb);
    unsigned short* hc1 = (unsigned short*)(ws + off_hc1);
    unsigned short* hc2 = (unsigned short*)(ws + off_hc2);
    u64*            hpp = (u64*)(ws + off_hpp);

    embed_k<<<8192, 256, 0, stream>>>(x, emb, h0);

    // layer 0
    gemm_xw<<<2048, 512, 0, stream>>>(h0, Wih0f, bih0f, bhh0f, xwf, BB * TT, EE);
    gemm_xw<<<2048, 512, 0, stream>>>(h0, Wih0b, bih0b, bhh0b, xwb, BB * TT, EE);
    (void)hipMemsetAsync(ws + off_hpp, 0, 524288, stream);
    lstm_scan<<<256, 256, 0, stream>>>(Whh0f, Whh0b, xwf, xwb, hc1, hpp);

    // layer 1
    gemm_xw<<<2048, 512, 0, stream>>>(hc1, Wih1f, bih1f, bhh1f, xwf, BB * TT, 1024);
    gemm_xw<<<2048, 512, 0, stream>>>(hc1, Wih1b, bih1b, bhh1b, xwb, BB * TT, 1024);
    (void)hipMemsetAsync(ws + off_hpp, 0, 524288, stream);
    lstm_scan<<<256, 256, 0, stream>>>(Whh1f, Whh1b, xwf, xwb, hc2, hpp);

    classifier_k<<<2048, 256, 0, stream>>>(hc2, truth, tf, Wc, bc, out);
}